// Round 1
// 426.039 us; speedup vs baseline: 1.0592x; 1.0592x over previous
//
#include <hip/hip_runtime.h>
#include <math.h>

#define NROW 8192
#define IN_F 256
#define OUT_F 128
#define SLOPE 0.1f
#define SEGS 256          // 256 segments x 32 rows
#define SEGROWS 32

typedef float f32x4 __attribute__((ext_vector_type(4)));

__device__ __forceinline__ float lrelu(float x) { return x > 0.f ? x : SLOPE * x; }

// ---------------------------------------------------------------- kA: h = doc@Ww^T + Wb, plus s_src/s_dst/E1/E2 per row
// Register-blocked: each thread computes 2 rows x 4 cols. LDS doc-read traffic
// drops 4x vs 1-col/thread (1 GB -> 256 MB total). W streams hit L1 (2 KB hot
// working set per k-step per block).
__global__ __launch_bounds__(256) void kA_h_s(const float* __restrict__ doc,
                                              const float* __restrict__ Ww,
                                              const float* __restrict__ Wb,
                                              const float* __restrict__ aw,
                                              float* __restrict__ h,
                                              float* __restrict__ s_src,
                                              float* __restrict__ s_dst,
                                              float* __restrict__ E1,
                                              float* __restrict__ E2) {
    __shared__ float4 sdoc[16][64];  // 16 rows x 256 floats = 16KB
    const int t = threadIdx.x;
    const int rowBase = blockIdx.x * 16;
    const float4* doc4 = (const float4*)(doc + (size_t)rowBase * IN_F);
    float4* sflat = &sdoc[0][0];
    for (int i = t; i < 16 * 64; i += 256) sflat[i] = doc4[i];
    __syncthreads();
    const int cq = t & 31;           // column quad: cols 4*cq .. 4*cq+3
    const int rg = t >> 5;           // row pair:    rows 2*rg, 2*rg+1
    const float4* w0 = (const float4*)(Ww + (size_t)(4 * cq + 0) * IN_F);
    const float4* w1 = (const float4*)(Ww + (size_t)(4 * cq + 1) * IN_F);
    const float4* w2 = (const float4*)(Ww + (size_t)(4 * cq + 2) * IN_F);
    const float4* w3 = (const float4*)(Ww + (size_t)(4 * cq + 3) * IN_F);
    float a00 = 0.f, a01 = 0.f, a02 = 0.f, a03 = 0.f;
    float a10 = 0.f, a11 = 0.f, a12 = 0.f, a13 = 0.f;
#pragma unroll 4
    for (int k = 0; k < 64; ++k) {
        const float4 d0 = sdoc[2 * rg + 0][k];
        const float4 d1 = sdoc[2 * rg + 1][k];
        float4 w;
        w = w0[k];
        a00 += d0.x * w.x + d0.y * w.y + d0.z * w.z + d0.w * w.w;
        a10 += d1.x * w.x + d1.y * w.y + d1.z * w.z + d1.w * w.w;
        w = w1[k];
        a01 += d0.x * w.x + d0.y * w.y + d0.z * w.z + d0.w * w.w;
        a11 += d1.x * w.x + d1.y * w.y + d1.z * w.z + d1.w * w.w;
        w = w2[k];
        a02 += d0.x * w.x + d0.y * w.y + d0.z * w.z + d0.w * w.w;
        a12 += d1.x * w.x + d1.y * w.y + d1.z * w.z + d1.w * w.w;
        w = w3[k];
        a03 += d0.x * w.x + d0.y * w.y + d0.z * w.z + d0.w * w.w;
        a13 += d1.x * w.x + d1.y * w.y + d1.z * w.z + d1.w * w.w;
    }
    const float4 wb4 = ((const float4*)Wb)[cq];
    const float4 as4 = ((const float4*)aw)[cq];
    const float4 ad4 = ((const float4*)(aw + OUT_F))[cq];

#define KA_EPILOG(A0, A1, A2, A3, RR)                                           \
    do {                                                                        \
        float4 hv;                                                              \
        hv.x = (A0) + wb4.x; hv.y = (A1) + wb4.y;                               \
        hv.z = (A2) + wb4.z; hv.w = (A3) + wb4.w;                               \
        const int row = rowBase + 2 * rg + (RR);                                \
        ((float4*)(h + (size_t)row * OUT_F))[cq] = hv;                          \
        float ps = hv.x * as4.x + hv.y * as4.y + hv.z * as4.z + hv.w * as4.w;   \
        float pd = hv.x * ad4.x + hv.y * ad4.y + hv.z * ad4.z + hv.w * ad4.w;   \
        for (int off = 16; off; off >>= 1) {                                    \
            ps += __shfl_down(ps, off, 32);                                     \
            pd += __shfl_down(pd, off, 32);                                     \
        }                                                                       \
        if (cq == 0) {                                                          \
            s_src[row] = ps;                                                    \
            s_dst[row] = pd;                                                    \
            E1[row] = expf(pd);                                                 \
            E2[row] = expf(SLOPE * pd);                                         \
        }                                                                       \
    } while (0)

    KA_EPILOG(a00, a01, a02, a03, 0);
    KA_EPILOG(a10, a11, a12, a13, 1);
#undef KA_EPILOG
}

// ---------------------------------------------------------------- kBC: blocks 0..255 rank -> perm; block 256 top-2 of s_dst
__global__ __launch_bounds__(256) void kBC_rank_top2(const float* __restrict__ sdst,
                                                     float* __restrict__ red,
                                                     int* __restrict__ perm) {
    const int t = threadIdx.x;
    if (blockIdx.x == SEGS) {
        // top-2 max of s_dst (+argmax)
        float m1 = -1e30f, m2 = -1e30f; int i1 = 0;
        for (int j = t; j < NROW; j += 256) {
            const float v = sdst[j];
            if (v > m1) { m2 = m1; m1 = v; i1 = j; }
            else if (v > m2) { m2 = v; }
        }
        __shared__ float sm1[256], sm2[256];
        __shared__ int si[256];
        sm1[t] = m1; sm2[t] = m2; si[t] = i1;
        __syncthreads();
        for (int s = 128; s > 0; s >>= 1) {
            if (t < s) {
                const float om1 = sm1[t + s], om2 = sm2[t + s];
                const int oi = si[t + s];
                if (om1 > sm1[t]) {
                    sm2[t] = fmaxf(sm1[t], om2);
                    sm1[t] = om1; si[t] = oi;
                } else {
                    sm2[t] = fmaxf(sm2[t], om1);
                }
            }
            __syncthreads();
        }
        if (t == 0) { red[0] = sm1[0]; red[1] = sm2[0]; red[2] = __int_as_float(si[0]); }
    } else {
        // rank -> permutation (ascending s_dst), 32 rows/block
        __shared__ float sd[NROW];       // 32 KB
        {
            float4* sd4 = (float4*)sd;
            const float4* g4 = (const float4*)sdst;
            for (int q = t; q < NROW / 4; q += 256) sd4[q] = g4[q];
        }
        __syncthreads();
        const int wave = t >> 6, lane = t & 63;
        const int base = blockIdx.x * 32 + wave * 8;
        float rv[8]; int ri[8]; int cnt[8];
#pragma unroll
        for (int r = 0; r < 8; ++r) { ri[r] = base + r; rv[r] = sd[ri[r]]; cnt[r] = 0; }
        for (int j = lane; j < NROW; j += 64) {
            const float v = sd[j];
#pragma unroll
            for (int r = 0; r < 8; ++r)
                cnt[r] += (v < rv[r] || (v == rv[r] && j < ri[r])) ? 1 : 0;
        }
#pragma unroll
        for (int r = 0; r < 8; ++r)
            for (int off = 32; off; off >>= 1) cnt[r] += __shfl_down(cnt[r], off);
        if (lane == 0) {
#pragma unroll
            for (int r = 0; r < 8; ++r) perm[cnt[r]] = ri[r];
        }
    }
}

// ---------------------------------------------------------------- kD: gather sortedS/E1s/E2s + per-segment column sums
// One block per segment (grid 256, was 64): full CU coverage, perm/E staged in
// LDS so the 16 h-row gathers per thread issue independently.
__global__ __launch_bounds__(256) void kD_gseg(const int* __restrict__ perm,
                                               const float* __restrict__ E1,
                                               const float* __restrict__ E2,
                                               const float* __restrict__ sdst,
                                               const float* __restrict__ h,
                                               float* __restrict__ sortedS,
                                               float* __restrict__ E1s,
                                               float* __restrict__ E2s,
                                               float* __restrict__ seg1,
                                               float* __restrict__ seg2) {
    __shared__ int sp[SEGROWS];
    __shared__ float se1[SEGROWS], se2[SEGROWS];
    __shared__ float part[2][OUT_F][2];   // [half][col][arr] = 2 KB
    const int t = threadIdx.x;
    const int s = blockIdx.x;
    const int r0 = s * SEGROWS;
    if (t < SEGROWS) {
        const int i = perm[r0 + t];
        sp[t] = i;
        const float e1 = E1[i], e2 = E2[i];
        se1[t] = e1; se2[t] = e2;
        sortedS[r0 + t] = sdst[i];
        E1s[r0 + t] = e1;
        E2s[r0 + t] = e2;
    }
    __syncthreads();
    const int c = t & 127;
    const int half = t >> 7;
    float a1 = 0.f, a2 = 0.f;
#pragma unroll
    for (int rr2 = 0; rr2 < 16; ++rr2) {
        const int rr = half * 16 + rr2;
        const float hv = h[(size_t)sp[rr] * OUT_F + c];
        a1 += se1[rr] * hv;
        a2 += se2[rr] * hv;
    }
    part[half][c][0] = a1;
    part[half][c][1] = a2;
    __syncthreads();
    if (t < 128) {
        seg1[(size_t)s * OUT_F + t] = part[0][t][0] + part[1][t][0];
    } else {
        const int c2 = t - 128;
        seg2[(size_t)s * OUT_F + c2] = part[0][c2][1] + part[1][c2][1];
    }
}

// ---------------------------------------------------------------- kE: blocks 0..255 -> seg offset scans; 256 -> Psuf; 257 -> Qpre
__global__ __launch_bounds__(256) void kE_scan(const float* __restrict__ seg1,
                                               const float* __restrict__ seg2,
                                               const float* __restrict__ E1s,
                                               const float* __restrict__ E2s,
                                               float* __restrict__ segUo,
                                               float* __restrict__ segVo,
                                               float* __restrict__ Psuf,
                                               float* __restrict__ Qpre) {
    const int p = blockIdx.x;
    const int t = threadIdx.x;
    if (p < 256) {
        const int arr = p >> 7;       // 0: seg1 suffix-excl, 1: seg2 prefix-excl
        const int col = p & 127;
        const float* src = arr ? seg2 : seg1;
        const float x = src[(size_t)t * OUT_F + col];
        __shared__ float buf[256];
        const int j = arr ? t : (255 - t);   // reverse for suffix scan
        buf[j] = x;
        __syncthreads();
        for (int off = 1; off < 256; off <<= 1) {
            const float add = (j >= off) ? buf[j - off] : 0.f;
            __syncthreads();
            buf[j] += add;
            __syncthreads();
        }
        const float excl = buf[j] - x;
        float* dst = arr ? segVo : segUo;
        dst[(size_t)t * OUT_F + col] = excl;
    } else if (p == 256) {
        // Psuf: suffix-inclusive scan of E1s, Psuf[NROW]=0
        __shared__ float pp[256];
        const int r0 = t * 32;
        float a = 0.f;
        for (int rr = 0; rr < 32; ++rr) a += E1s[r0 + rr];
        pp[t] = a;
        __syncthreads();
        float off = 0.f;
        for (int t2 = t + 1; t2 < 256; ++t2) off += pp[t2];
        float run = off;
        for (int rr = 31; rr >= 0; --rr) { run += E1s[r0 + rr]; Psuf[r0 + rr] = run; }
        if (t == 0) Psuf[NROW] = 0.f;
    } else {
        // Qpre: prefix-exclusive scan of E2s, Qpre[NROW]=total
        __shared__ float pp[256];
        const int r0 = t * 32;
        float a = 0.f;
        for (int rr = 0; rr < 32; ++rr) a += E2s[r0 + rr];
        pp[t] = a;
        __syncthreads();
        float off = 0.f;
        for (int t2 = 0; t2 < t; ++t2) off += pp[t2];
        float rv = off;
        for (int rr = 0; rr < 32; ++rr) { Qpre[r0 + rr] = rv; rv += E2s[r0 + rr]; }
        if (t == 255) Qpre[NROW] = rv;
    }
}

// ---------------------------------------------------------------- kF: U (suffix-incl of E1s*h) and V (prefix-excl of E2s*h)
// One block per segment (grid 256, was 128). Waves 0-1 do the U backward scan,
// waves 2-3 do the V forward scan -> serial scan length halved per thread.
__global__ __launch_bounds__(256) void kF_uv(const int* __restrict__ perm,
                                             const float* __restrict__ h,
                                             const float* __restrict__ E1s,
                                             const float* __restrict__ E2s,
                                             const float* __restrict__ segUo,
                                             const float* __restrict__ segVo,
                                             float* __restrict__ U,
                                             float* __restrict__ V) {
    __shared__ int sp[SEGROWS];
    __shared__ float se1[SEGROWS], se2[SEGROWS];
    __shared__ float sUo[OUT_F], sVo[OUT_F];
    const int t = threadIdx.x;
    const int s = blockIdx.x;
    const int r0 = s * SEGROWS;
    if (t < 128) sUo[t] = segUo[(size_t)s * OUT_F + t];
    else         sVo[t - 128] = segVo[(size_t)s * OUT_F + (t - 128)];
    if (t < SEGROWS) {
        sp[t] = perm[r0 + t];
        se1[t] = E1s[r0 + t];
        se2[t] = E2s[r0 + t];
    }
    __syncthreads();
    const int c = t & 127;
    const int doV = t >> 7;
    float xv[SEGROWS];
#pragma unroll
    for (int rr = 0; rr < SEGROWS; ++rr)
        xv[rr] = h[(size_t)sp[rr] * OUT_F + c];
    if (!doV) {
        float run = sUo[c];
#pragma unroll
        for (int rr = SEGROWS - 1; rr >= 0; --rr) {
            run += se1[rr] * xv[rr];
            U[(size_t)(r0 + rr) * OUT_F + c] = run;
        }
        if (s == SEGS - 1) U[(size_t)NROW * OUT_F + c] = 0.f;
    } else {
        float rv = sVo[c];
#pragma unroll
        for (int rr = 0; rr < SEGROWS; ++rr) {
            V[(size_t)(r0 + rr) * OUT_F + c] = rv;
            rv += se2[rr] * xv[rr];
        }
        if (s == SEGS - 1) V[(size_t)NROW * OUT_F + c] = rv;
    }
}

// ---------------------------------------------------------------- kG: row constants (A,B,rZ,T) + h_out
__global__ __launch_bounds__(256) void kG_hout(const float* __restrict__ s_src,
                                               const float* __restrict__ sdst,
                                               const float* __restrict__ sortedS,
                                               const float* __restrict__ Psuf,
                                               const float* __restrict__ Qpre,
                                               const float* __restrict__ red,
                                               const float* __restrict__ ab,
                                               const int* __restrict__ selfLink,
                                               const float* __restrict__ U,
                                               const float* __restrict__ V,
                                               const float* __restrict__ h,
                                               float* __restrict__ A,
                                               float* __restrict__ B,
                                               float* __restrict__ rZ,
                                               float* __restrict__ T,
                                               float* __restrict__ hout) {
    const int t = threadIdx.x;
    const int i = blockIdx.x * 2 + (t >> 7);
    const int c = t & 127;
    const bool mask = (selfLink[0] == 0);
    const float tt = s_src[i] + ab[0];
    const float M1 = red[0], M2 = red[1];
    const int i1 = __float_as_int(red[2]);
    const float M = (mask && i1 == i) ? M2 : M1;
    const float m = lrelu(tt + M);
    const float Ai = expf(tt - m);
    const float Bi = expf(SLOPE * tt - m);
    const float eii = mask ? expf(lrelu(tt + sdst[i]) - m) : 0.f;
    const float thr = -tt;
    int lo = 0, hi = NROW;
    while (lo < hi) {
        const int mid = (lo + hi) >> 1;
        if (sortedS[mid] > thr) hi = mid; else lo = mid + 1;
    }
    const int k = lo;
    const float Z = Ai * Psuf[k] + Bi * Qpre[k] - eii;
    const float rZi = 1.f / Z;
    const float val = Ai * U[(size_t)k * OUT_F + c] + Bi * V[(size_t)k * OUT_F + c]
                    - eii * h[(size_t)i * OUT_F + c];
    hout[(size_t)i * OUT_F + c] = lrelu(val * rZi);
    if (c == 0) { A[i] = Ai; B[i] = Bi; rZ[i] = rZi; T[i] = tt; }
}

// ---------------------------------------------------------------- kH: stream the att matrix
// j-slice (sdst/E1/E2) held in registers and reused across all 16 rows of the
// block (no LDS data path). Nontemporal stores: att is write-once, keep it out
// of L2.
#define RH 16
__global__ __launch_bounds__(256) void kH_att(const float* __restrict__ sdst,
                                              const float* __restrict__ E1,
                                              const float* __restrict__ E2,
                                              const float* __restrict__ A,
                                              const float* __restrict__ B,
                                              const float* __restrict__ rZ,
                                              const float* __restrict__ T,
                                              const int* __restrict__ selfLink,
                                              float* __restrict__ att) {
    __shared__ float rA[RH], rB[RH], rT[RH];
    const int t = threadIdx.x;
    const int rowBase = blockIdx.x * RH;
    if (t < RH) {
        const int i = rowBase + t;
        const float z = rZ[i];
        rA[t] = A[i] * z;
        rB[t] = B[i] * z;
        rT[t] = -T[i];
    }
    __syncthreads();
    const bool mask = (selfLink[0] == 0);
    const f32x4* s4p = (const f32x4*)sdst;
    const f32x4* e1p = (const f32x4*)E1;
    const f32x4* e2p = (const f32x4*)E2;
    for (int it = 0; it < NROW / (4 * 256); ++it) {   // 8 iterations
        const int q = it * 256 + t;                   // float4 column index
        const f32x4 s4 = s4p[q];
        const f32x4 e1 = e1p[q];
        const f32x4 e2 = e2p[q];
        const int j0 = q * 4;
#pragma unroll
        for (int r = 0; r < RH; ++r) {
            const float a = rA[r], b = rB[r], thr = rT[r];
            f32x4 o;
            o.x = s4.x > thr ? a * e1.x : b * e2.x;
            o.y = s4.y > thr ? a * e1.y : b * e2.y;
            o.z = s4.z > thr ? a * e1.z : b * e2.z;
            o.w = s4.w > thr ? a * e1.w : b * e2.w;
            const int i = rowBase + r;
            const int d = i - j0;
            if (mask && ((unsigned)d < 4u)) {
                if (d == 0) o.x = 0.f;
                else if (d == 1) o.y = 0.f;
                else if (d == 2) o.z = 0.f;
                else o.w = 0.f;
            }
            __builtin_nontemporal_store(o, (f32x4*)(att + (size_t)i * NROW) + q);
        }
    }
}

// ----------------------------------------------------------------
extern "C" void kernel_launch(void* const* d_in, const int* in_sizes, int n_in,
                              void* d_out, int out_size, void* d_ws, size_t ws_size,
                              hipStream_t stream) {
    const float* doc = (const float*)d_in[0];
    const float* Ww  = (const float*)d_in[1];
    const float* Wb  = (const float*)d_in[2];
    const float* aw  = (const float*)d_in[3];
    const float* ab  = (const float*)d_in[4];
    const int* selfLink = (const int*)d_in[5];

    float* out  = (float*)d_out;
    float* hout = out;                                   // NROW*OUT_F
    float* att  = out + (size_t)NROW * OUT_F;            // NROW*NROW

    // Big scratch (h, U, V) lives inside the att output region: every consumer
    // runs before kH overwrites it. 12.6 MB << 268 MB.
    float* h = att;                                      // NROW*OUT_F
    float* U = att + 1048576;                            // (NROW+1)*OUT_F
    float* V = att + 1048576 + 1048704;                  // (NROW+1)*OUT_F

    float* ws = (float*)d_ws;
    float* s_src   = ws;            // 8192
    float* s_dst   = ws + 8192;     // 8192
    float* E1      = ws + 16384;    // 8192
    float* E2      = ws + 24576;    // 8192
    float* sortedS = ws + 32768;    // 8192
    float* E1s     = ws + 40960;    // 8192
    float* E2s     = ws + 49152;    // 8192
    float* Aarr    = ws + 57344;    // 8192
    float* Barr    = ws + 65536;    // 8192
    float* rZ      = ws + 73728;    // 8192
    float* Tarr    = ws + 81920;    // 8192
    int*   perm    = (int*)(ws + 90112);   // 8192
    float* seg1    = ws + 98304;    // SEGS*OUT_F = 32768
    float* seg2    = ws + 131072;   // 32768
    float* segUo   = ws + 163840;   // 32768
    float* segVo   = ws + 196608;   // 32768
    float* Psuf    = ws + 229376;   // 8193
    float* Qpre    = ws + 237632;   // 8193
    float* red     = ws + 245888;   // 3

    kA_h_s       <<<512,  256, 0, stream>>>(doc, Ww, Wb, aw, h, s_src, s_dst, E1, E2);
    kBC_rank_top2<<<257,  256, 0, stream>>>(s_dst, red, perm);
    kD_gseg      <<<256,  256, 0, stream>>>(perm, E1, E2, s_dst, h, sortedS, E1s, E2s, seg1, seg2);
    kE_scan      <<<258,  256, 0, stream>>>(seg1, seg2, E1s, E2s, segUo, segVo, Psuf, Qpre);
    kF_uv        <<<256,  256, 0, stream>>>(perm, h, E1s, E2s, segUo, segVo, U, V);
    kG_hout      <<<4096, 256, 0, stream>>>(s_src, s_dst, sortedS, Psuf, Qpre, red, ab, selfLink,
                                            U, V, h, Aarr, Barr, rZ, Tarr, hout);
    kH_att       <<<512,  256, 0, stream>>>(s_dst, E1, E2, Aarr, Barr, rZ, Tarr, selfLink, att);
}

// Round 2
// 415.312 us; speedup vs baseline: 1.0866x; 1.0258x over previous
//
#include <hip/hip_runtime.h>
#include <math.h>

#define NROW 8192
#define IN_F 256
#define OUT_F 128
#define SLOPE 0.1f
#define SEGS 256          // 256 segments x 32 rows
#define SEGROWS 32

typedef float f32x4 __attribute__((ext_vector_type(4)));

__device__ __forceinline__ float lrelu(float x) { return x > 0.f ? x : SLOPE * x; }

// ---------------------------------------------------------------- kA: h = doc@Ww^T + Wb, plus s_src/s_dst/E1/E2 per row
// Register-blocked: each thread computes 2 rows x 4 cols.
__global__ __launch_bounds__(256) void kA_h_s(const float* __restrict__ doc,
                                              const float* __restrict__ Ww,
                                              const float* __restrict__ Wb,
                                              const float* __restrict__ aw,
                                              float* __restrict__ h,
                                              float* __restrict__ s_src,
                                              float* __restrict__ s_dst,
                                              float* __restrict__ E1,
                                              float* __restrict__ E2) {
    __shared__ float4 sdoc[16][64];  // 16 rows x 256 floats = 16KB
    const int t = threadIdx.x;
    const int rowBase = blockIdx.x * 16;
    const float4* doc4 = (const float4*)(doc + (size_t)rowBase * IN_F);
    float4* sflat = &sdoc[0][0];
    for (int i = t; i < 16 * 64; i += 256) sflat[i] = doc4[i];
    __syncthreads();
    const int cq = t & 31;           // column quad: cols 4*cq .. 4*cq+3
    const int rg = t >> 5;           // row pair:    rows 2*rg, 2*rg+1
    const float4* w0 = (const float4*)(Ww + (size_t)(4 * cq + 0) * IN_F);
    const float4* w1 = (const float4*)(Ww + (size_t)(4 * cq + 1) * IN_F);
    const float4* w2 = (const float4*)(Ww + (size_t)(4 * cq + 2) * IN_F);
    const float4* w3 = (const float4*)(Ww + (size_t)(4 * cq + 3) * IN_F);
    float a00 = 0.f, a01 = 0.f, a02 = 0.f, a03 = 0.f;
    float a10 = 0.f, a11 = 0.f, a12 = 0.f, a13 = 0.f;
#pragma unroll 4
    for (int k = 0; k < 64; ++k) {
        const float4 d0 = sdoc[2 * rg + 0][k];
        const float4 d1 = sdoc[2 * rg + 1][k];
        float4 w;
        w = w0[k];
        a00 += d0.x * w.x + d0.y * w.y + d0.z * w.z + d0.w * w.w;
        a10 += d1.x * w.x + d1.y * w.y + d1.z * w.z + d1.w * w.w;
        w = w1[k];
        a01 += d0.x * w.x + d0.y * w.y + d0.z * w.z + d0.w * w.w;
        a11 += d1.x * w.x + d1.y * w.y + d1.z * w.z + d1.w * w.w;
        w = w2[k];
        a02 += d0.x * w.x + d0.y * w.y + d0.z * w.z + d0.w * w.w;
        a12 += d1.x * w.x + d1.y * w.y + d1.z * w.z + d1.w * w.w;
        w = w3[k];
        a03 += d0.x * w.x + d0.y * w.y + d0.z * w.z + d0.w * w.w;
        a13 += d1.x * w.x + d1.y * w.y + d1.z * w.z + d1.w * w.w;
    }
    const float4 wb4 = ((const float4*)Wb)[cq];
    const float4 as4 = ((const float4*)aw)[cq];
    const float4 ad4 = ((const float4*)(aw + OUT_F))[cq];

#define KA_EPILOG(A0, A1, A2, A3, RR)                                           \
    do {                                                                        \
        float4 hv;                                                              \
        hv.x = (A0) + wb4.x; hv.y = (A1) + wb4.y;                               \
        hv.z = (A2) + wb4.z; hv.w = (A3) + wb4.w;                               \
        const int row = rowBase + 2 * rg + (RR);                                \
        ((float4*)(h + (size_t)row * OUT_F))[cq] = hv;                          \
        float ps = hv.x * as4.x + hv.y * as4.y + hv.z * as4.z + hv.w * as4.w;   \
        float pd = hv.x * ad4.x + hv.y * ad4.y + hv.z * ad4.z + hv.w * ad4.w;   \
        for (int off = 16; off; off >>= 1) {                                    \
            ps += __shfl_down(ps, off, 32);                                     \
            pd += __shfl_down(pd, off, 32);                                     \
        }                                                                       \
        if (cq == 0) {                                                          \
            s_src[row] = ps;                                                    \
            s_dst[row] = pd;                                                    \
            E1[row] = expf(pd);                                                 \
            E2[row] = expf(SLOPE * pd);                                         \
        }                                                                       \
    } while (0)

    KA_EPILOG(a00, a01, a02, a03, 0);
    KA_EPILOG(a10, a11, a12, a13, 1);
#undef KA_EPILOG
}

// ---------------------------------------------------------------- kBC: blocks 0..255 rank -> perm; block 256 top-2 of s_dst
__global__ __launch_bounds__(256) void kBC_rank_top2(const float* __restrict__ sdst,
                                                     float* __restrict__ red,
                                                     int* __restrict__ perm) {
    const int t = threadIdx.x;
    if (blockIdx.x == SEGS) {
        // top-2 max of s_dst (+argmax)
        float m1 = -1e30f, m2 = -1e30f; int i1 = 0;
        for (int j = t; j < NROW; j += 256) {
            const float v = sdst[j];
            if (v > m1) { m2 = m1; m1 = v; i1 = j; }
            else if (v > m2) { m2 = v; }
        }
        __shared__ float sm1[256], sm2[256];
        __shared__ int si[256];
        sm1[t] = m1; sm2[t] = m2; si[t] = i1;
        __syncthreads();
        for (int s = 128; s > 0; s >>= 1) {
            if (t < s) {
                const float om1 = sm1[t + s], om2 = sm2[t + s];
                const int oi = si[t + s];
                if (om1 > sm1[t]) {
                    sm2[t] = fmaxf(sm1[t], om2);
                    sm1[t] = om1; si[t] = oi;
                } else {
                    sm2[t] = fmaxf(sm2[t], om1);
                }
            }
            __syncthreads();
        }
        if (t == 0) { red[0] = sm1[0]; red[1] = sm2[0]; red[2] = __int_as_float(si[0]); }
    } else {
        // rank -> permutation (ascending s_dst), 32 rows/block
        __shared__ float sd[NROW];       // 32 KB
        {
            float4* sd4 = (float4*)sd;
            const float4* g4 = (const float4*)sdst;
            for (int q = t; q < NROW / 4; q += 256) sd4[q] = g4[q];
        }
        __syncthreads();
        const int wave = t >> 6, lane = t & 63;
        const int base = blockIdx.x * 32 + wave * 8;
        float rv[8]; int ri[8]; int cnt[8];
#pragma unroll
        for (int r = 0; r < 8; ++r) { ri[r] = base + r; rv[r] = sd[ri[r]]; cnt[r] = 0; }
        for (int j = lane; j < NROW; j += 64) {
            const float v = sd[j];
#pragma unroll
            for (int r = 0; r < 8; ++r)
                cnt[r] += (v < rv[r] || (v == rv[r] && j < ri[r])) ? 1 : 0;
        }
#pragma unroll
        for (int r = 0; r < 8; ++r)
            for (int off = 32; off; off >>= 1) cnt[r] += __shfl_down(cnt[r], off);
        if (lane == 0) {
#pragma unroll
            for (int r = 0; r < 8; ++r) perm[cnt[r]] = ri[r];
        }
    }
}

// ---------------------------------------------------------------- kD: gather sortedS/E1s/E2s + per-segment column sums
__global__ __launch_bounds__(256) void kD_gseg(const int* __restrict__ perm,
                                               const float* __restrict__ E1,
                                               const float* __restrict__ E2,
                                               const float* __restrict__ sdst,
                                               const float* __restrict__ h,
                                               float* __restrict__ sortedS,
                                               float* __restrict__ E1s,
                                               float* __restrict__ E2s,
                                               float* __restrict__ seg1,
                                               float* __restrict__ seg2) {
    __shared__ int sp[SEGROWS];
    __shared__ float se1[SEGROWS], se2[SEGROWS];
    __shared__ float part[2][OUT_F][2];   // [half][col][arr] = 2 KB
    const int t = threadIdx.x;
    const int s = blockIdx.x;
    const int r0 = s * SEGROWS;
    if (t < SEGROWS) {
        const int i = perm[r0 + t];
        sp[t] = i;
        const float e1 = E1[i], e2 = E2[i];
        se1[t] = e1; se2[t] = e2;
        sortedS[r0 + t] = sdst[i];
        E1s[r0 + t] = e1;
        E2s[r0 + t] = e2;
    }
    __syncthreads();
    const int c = t & 127;
    const int half = t >> 7;
    float a1 = 0.f, a2 = 0.f;
#pragma unroll
    for (int rr2 = 0; rr2 < 16; ++rr2) {
        const int rr = half * 16 + rr2;
        const float hv = h[(size_t)sp[rr] * OUT_F + c];
        a1 += se1[rr] * hv;
        a2 += se2[rr] * hv;
    }
    part[half][c][0] = a1;
    part[half][c][1] = a2;
    __syncthreads();
    if (t < 128) {
        seg1[(size_t)s * OUT_F + t] = part[0][t][0] + part[1][t][0];
    } else {
        const int c2 = t - 128;
        seg2[(size_t)s * OUT_F + c2] = part[0][c2][1] + part[1][c2][1];
    }
}

// ---------------------------------------------------------------- kE: blocks 0..255 -> seg offset scans; 256 -> Psuf; 257 -> Qpre
__global__ __launch_bounds__(256) void kE_scan(const float* __restrict__ seg1,
                                               const float* __restrict__ seg2,
                                               const float* __restrict__ E1s,
                                               const float* __restrict__ E2s,
                                               float* __restrict__ segUo,
                                               float* __restrict__ segVo,
                                               float* __restrict__ Psuf,
                                               float* __restrict__ Qpre) {
    const int p = blockIdx.x;
    const int t = threadIdx.x;
    if (p < 256) {
        const int arr = p >> 7;       // 0: seg1 suffix-excl, 1: seg2 prefix-excl
        const int col = p & 127;
        const float* src = arr ? seg2 : seg1;
        const float x = src[(size_t)t * OUT_F + col];
        __shared__ float buf[256];
        const int j = arr ? t : (255 - t);   // reverse for suffix scan
        buf[j] = x;
        __syncthreads();
        for (int off = 1; off < 256; off <<= 1) {
            const float add = (j >= off) ? buf[j - off] : 0.f;
            __syncthreads();
            buf[j] += add;
            __syncthreads();
        }
        const float excl = buf[j] - x;
        float* dst = arr ? segVo : segUo;
        dst[(size_t)t * OUT_F + col] = excl;
    } else if (p == 256) {
        // Psuf: suffix-inclusive scan of E1s, Psuf[NROW]=0
        __shared__ float pp[256];
        const int r0 = t * 32;
        float a = 0.f;
        for (int rr = 0; rr < 32; ++rr) a += E1s[r0 + rr];
        pp[t] = a;
        __syncthreads();
        float off = 0.f;
        for (int t2 = t + 1; t2 < 256; ++t2) off += pp[t2];
        float run = off;
        for (int rr = 31; rr >= 0; --rr) { run += E1s[r0 + rr]; Psuf[r0 + rr] = run; }
        if (t == 0) Psuf[NROW] = 0.f;
    } else {
        // Qpre: prefix-exclusive scan of E2s, Qpre[NROW]=total
        __shared__ float pp[256];
        const int r0 = t * 32;
        float a = 0.f;
        for (int rr = 0; rr < 32; ++rr) a += E2s[r0 + rr];
        pp[t] = a;
        __syncthreads();
        float off = 0.f;
        for (int t2 = 0; t2 < t; ++t2) off += pp[t2];
        float rv = off;
        for (int rr = 0; rr < 32; ++rr) { Qpre[r0 + rr] = rv; rv += E2s[r0 + rr]; }
        if (t == 255) Qpre[NROW] = rv;
    }
}

// ---------------------------------------------------------------- kF: U (suffix-incl of E1s*h) and V (prefix-excl of E2s*h)
__global__ __launch_bounds__(256) void kF_uv(const int* __restrict__ perm,
                                             const float* __restrict__ h,
                                             const float* __restrict__ E1s,
                                             const float* __restrict__ E2s,
                                             const float* __restrict__ segUo,
                                             const float* __restrict__ segVo,
                                             float* __restrict__ U,
                                             float* __restrict__ V) {
    __shared__ int sp[SEGROWS];
    __shared__ float se1[SEGROWS], se2[SEGROWS];
    __shared__ float sUo[OUT_F], sVo[OUT_F];
    const int t = threadIdx.x;
    const int s = blockIdx.x;
    const int r0 = s * SEGROWS;
    if (t < 128) sUo[t] = segUo[(size_t)s * OUT_F + t];
    else         sVo[t - 128] = segVo[(size_t)s * OUT_F + (t - 128)];
    if (t < SEGROWS) {
        sp[t] = perm[r0 + t];
        se1[t] = E1s[r0 + t];
        se2[t] = E2s[r0 + t];
    }
    __syncthreads();
    const int c = t & 127;
    const int doV = t >> 7;
    float xv[SEGROWS];
#pragma unroll
    for (int rr = 0; rr < SEGROWS; ++rr)
        xv[rr] = h[(size_t)sp[rr] * OUT_F + c];
    if (!doV) {
        float run = sUo[c];
#pragma unroll
        for (int rr = SEGROWS - 1; rr >= 0; --rr) {
            run += se1[rr] * xv[rr];
            U[(size_t)(r0 + rr) * OUT_F + c] = run;
        }
        if (s == SEGS - 1) U[(size_t)NROW * OUT_F + c] = 0.f;
    } else {
        float rv = sVo[c];
#pragma unroll
        for (int rr = 0; rr < SEGROWS; ++rr) {
            V[(size_t)(r0 + rr) * OUT_F + c] = rv;
            rv += se2[rr] * xv[rr];
        }
        if (s == SEGS - 1) V[(size_t)NROW * OUT_F + c] = rv;
    }
}

// ---------------------------------------------------------------- kGH (fused): row constants + hout + att stream
// sortedS staged in LDS -> binary search is 13 LDS probes instead of 13
// dependent global loads repeated by 128 threads. Row constants never touch
// global memory. Plain stores for att (the fill proves plain stores hit
// 6.3+ TB/s on this buffer; NT was unproven).
#define RH 16
__global__ __launch_bounds__(256) void kGH_hout_att(const float* __restrict__ s_src,
                                                    const float* __restrict__ sdst,
                                                    const float* __restrict__ sortedS,
                                                    const float* __restrict__ Psuf,
                                                    const float* __restrict__ Qpre,
                                                    const float* __restrict__ red,
                                                    const float* __restrict__ ab,
                                                    const int* __restrict__ selfLink,
                                                    const float* __restrict__ U,
                                                    const float* __restrict__ V,
                                                    const float* __restrict__ h,
                                                    const float* __restrict__ E1,
                                                    const float* __restrict__ E2,
                                                    float* __restrict__ hout,
                                                    float* __restrict__ att) {
    __shared__ float sS[NROW];           // 32 KB sorted thresholds
    __shared__ float sAi[RH], sBi[RH], srZ[RH], seii[RH];
    __shared__ int   sk[RH];
    __shared__ float rA[RH], rB[RH], rT[RH];
    const int t = threadIdx.x;
    const int rowBase = blockIdx.x * RH;
    {
        f32x4* d = (f32x4*)sS;
        const f32x4* s = (const f32x4*)sortedS;
        for (int q = t; q < NROW / 4; q += 256) d[q] = s[q];
    }
    __syncthreads();
    if (t < RH) {
        const int i = rowBase + t;
        const bool mask = (selfLink[0] == 0);
        const float tt = s_src[i] + ab[0];
        const float M1 = red[0], M2 = red[1];
        const int i1 = __float_as_int(red[2]);
        const float M = (mask && i1 == i) ? M2 : M1;
        const float m = lrelu(tt + M);
        const float Ai = expf(tt - m);
        const float Bi = expf(SLOPE * tt - m);
        const float eii = mask ? expf(lrelu(tt + sdst[i]) - m) : 0.f;
        const float thr = -tt;
        int lo = 0, hi = NROW;
        while (lo < hi) {
            const int mid = (lo + hi) >> 1;
            if (sS[mid] > thr) hi = mid; else lo = mid + 1;
        }
        const int k = lo;
        const float Z = Ai * Psuf[k] + Bi * Qpre[k] - eii;
        const float rZi = 1.f / Z;
        sAi[t] = Ai; sBi[t] = Bi; srZ[t] = rZi; seii[t] = eii; sk[t] = k;
        rA[t] = Ai * rZi; rB[t] = Bi * rZi; rT[t] = thr;
    }
    __syncthreads();
    // hout for this block's 16 rows (2 rows per pass, 128 cols each)
    {
        const int c = t & 127;
        const int half = t >> 7;
#pragma unroll
        for (int rp = 0; rp < RH / 2; ++rp) {
            const int r = rp * 2 + half;
            const int i = rowBase + r;
            const int k = sk[r];
            const float val = sAi[r] * U[(size_t)k * OUT_F + c]
                            + sBi[r] * V[(size_t)k * OUT_F + c]
                            - seii[r] * h[(size_t)i * OUT_F + c];
            hout[(size_t)i * OUT_F + c] = lrelu(val * srZ[r]);
        }
    }
    // att stream: j-slice in registers, reused across the 16 rows
    float cA[RH], cB[RH], cT[RH];
#pragma unroll
    for (int r = 0; r < RH; ++r) { cA[r] = rA[r]; cB[r] = rB[r]; cT[r] = rT[r]; }
    const bool mask = (selfLink[0] == 0);
    const f32x4* s4p = (const f32x4*)sdst;
    const f32x4* e1p = (const f32x4*)E1;
    const f32x4* e2p = (const f32x4*)E2;
    for (int it = 0; it < NROW / (4 * 256); ++it) {   // 8 iterations
        const int q = it * 256 + t;                   // float4 column index
        const f32x4 s4 = s4p[q];
        const f32x4 e1 = e1p[q];
        const f32x4 e2 = e2p[q];
        const int j0 = q * 4;
#pragma unroll
        for (int r = 0; r < RH; ++r) {
            const float a = cA[r], b = cB[r], thr = cT[r];
            f32x4 o;
            o.x = s4.x > thr ? a * e1.x : b * e2.x;
            o.y = s4.y > thr ? a * e1.y : b * e2.y;
            o.z = s4.z > thr ? a * e1.z : b * e2.z;
            o.w = s4.w > thr ? a * e1.w : b * e2.w;
            const int i = rowBase + r;
            const int d = i - j0;
            if (mask && ((unsigned)d < 4u)) {
                if (d == 0) o.x = 0.f;
                else if (d == 1) o.y = 0.f;
                else if (d == 2) o.z = 0.f;
                else o.w = 0.f;
            }
            *((f32x4*)(att + (size_t)i * NROW) + q) = o;
        }
    }
}

// ---------------------------------------------------------------- fallback kG: row constants (A,B,rZ,T) + h_out
__global__ __launch_bounds__(256) void kG_hout(const float* __restrict__ s_src,
                                               const float* __restrict__ sdst,
                                               const float* __restrict__ sortedS,
                                               const float* __restrict__ Psuf,
                                               const float* __restrict__ Qpre,
                                               const float* __restrict__ red,
                                               const float* __restrict__ ab,
                                               const int* __restrict__ selfLink,
                                               const float* __restrict__ U,
                                               const float* __restrict__ V,
                                               const float* __restrict__ h,
                                               float* __restrict__ A,
                                               float* __restrict__ B,
                                               float* __restrict__ rZ,
                                               float* __restrict__ T,
                                               float* __restrict__ hout) {
    const int t = threadIdx.x;
    const int i = blockIdx.x * 2 + (t >> 7);
    const int c = t & 127;
    const bool mask = (selfLink[0] == 0);
    const float tt = s_src[i] + ab[0];
    const float M1 = red[0], M2 = red[1];
    const int i1 = __float_as_int(red[2]);
    const float M = (mask && i1 == i) ? M2 : M1;
    const float m = lrelu(tt + M);
    const float Ai = expf(tt - m);
    const float Bi = expf(SLOPE * tt - m);
    const float eii = mask ? expf(lrelu(tt + sdst[i]) - m) : 0.f;
    const float thr = -tt;
    int lo = 0, hi = NROW;
    while (lo < hi) {
        const int mid = (lo + hi) >> 1;
        if (sortedS[mid] > thr) hi = mid; else lo = mid + 1;
    }
    const int k = lo;
    const float Z = Ai * Psuf[k] + Bi * Qpre[k] - eii;
    const float rZi = 1.f / Z;
    const float val = Ai * U[(size_t)k * OUT_F + c] + Bi * V[(size_t)k * OUT_F + c]
                    - eii * h[(size_t)i * OUT_F + c];
    hout[(size_t)i * OUT_F + c] = lrelu(val * rZi);
    if (c == 0) { A[i] = Ai; B[i] = Bi; rZ[i] = rZi; T[i] = tt; }
}

// ---------------------------------------------------------------- fallback kH: stream the att matrix
__global__ __launch_bounds__(256) void kH_att(const float* __restrict__ sdst,
                                              const float* __restrict__ E1,
                                              const float* __restrict__ E2,
                                              const float* __restrict__ A,
                                              const float* __restrict__ B,
                                              const float* __restrict__ rZ,
                                              const float* __restrict__ T,
                                              const int* __restrict__ selfLink,
                                              float* __restrict__ att) {
    __shared__ float rA[RH], rB[RH], rT[RH];
    const int t = threadIdx.x;
    const int rowBase = blockIdx.x * RH;
    if (t < RH) {
        const int i = rowBase + t;
        const float z = rZ[i];
        rA[t] = A[i] * z;
        rB[t] = B[i] * z;
        rT[t] = -T[i];
    }
    __syncthreads();
    const bool mask = (selfLink[0] == 0);
    const f32x4* s4p = (const f32x4*)sdst;
    const f32x4* e1p = (const f32x4*)E1;
    const f32x4* e2p = (const f32x4*)E2;
    for (int it = 0; it < NROW / (4 * 256); ++it) {
        const int q = it * 256 + t;
        const f32x4 s4 = s4p[q];
        const f32x4 e1 = e1p[q];
        const f32x4 e2 = e2p[q];
        const int j0 = q * 4;
#pragma unroll
        for (int r = 0; r < RH; ++r) {
            const float a = rA[r], b = rB[r], thr = rT[r];
            f32x4 o;
            o.x = s4.x > thr ? a * e1.x : b * e2.x;
            o.y = s4.y > thr ? a * e1.y : b * e2.y;
            o.z = s4.z > thr ? a * e1.z : b * e2.z;
            o.w = s4.w > thr ? a * e1.w : b * e2.w;
            const int i = rowBase + r;
            const int d = i - j0;
            if (mask && ((unsigned)d < 4u)) {
                if (d == 0) o.x = 0.f;
                else if (d == 1) o.y = 0.f;
                else if (d == 2) o.z = 0.f;
                else o.w = 0.f;
            }
            *((f32x4*)(att + (size_t)i * NROW) + q) = o;
        }
    }
}

// ----------------------------------------------------------------
extern "C" void kernel_launch(void* const* d_in, const int* in_sizes, int n_in,
                              void* d_out, int out_size, void* d_ws, size_t ws_size,
                              hipStream_t stream) {
    const float* doc = (const float*)d_in[0];
    const float* Ww  = (const float*)d_in[1];
    const float* Wb  = (const float*)d_in[2];
    const float* aw  = (const float*)d_in[3];
    const float* ab  = (const float*)d_in[4];
    const int* selfLink = (const int*)d_in[5];

    float* out  = (float*)d_out;
    float* hout = out;                                   // NROW*OUT_F
    float* att  = out + (size_t)NROW * OUT_F;            // NROW*NROW

    float* ws = (float*)d_ws;
    float* s_src   = ws;            // 8192
    float* s_dst   = ws + 8192;     // 8192
    float* E1      = ws + 16384;    // 8192
    float* E2      = ws + 24576;    // 8192
    float* sortedS = ws + 32768;    // 8192
    float* E1s     = ws + 40960;    // 8192
    float* E2s     = ws + 49152;    // 8192
    float* Aarr    = ws + 57344;    // 8192 (fallback path only)
    float* Barr    = ws + 65536;    // 8192 (fallback path only)
    float* rZ      = ws + 73728;    // 8192 (fallback path only)
    float* Tarr    = ws + 81920;    // 8192 (fallback path only)
    int*   perm    = (int*)(ws + 90112);   // 8192
    float* seg1    = ws + 98304;    // SEGS*OUT_F = 32768
    float* seg2    = ws + 131072;   // 32768
    float* segUo   = ws + 163840;   // 32768
    float* segVo   = ws + 196608;   // 32768
    float* Psuf    = ws + 229376;   // 8193
    float* Qpre    = ws + 237632;   // 8193
    float* red     = ws + 245888;   // 3

    const size_t hN  = (size_t)NROW * OUT_F;          // 1,048,576 floats
    const size_t uvN = (size_t)(NROW + 1) * OUT_F;    // 1,048,704 floats
    const size_t bigBase = 245952;                    // 64-aligned start for big scratch
    const size_t neededBytes = (bigBase + hN + 2 * uvN) * sizeof(float);  // ~13.6 MB
    const bool fused = (ws_size >= neededBytes);

    float *h, *U, *V;
    if (fused) {
        // Scratch in ws: no aliasing with att -> kG can fuse into the att streamer.
        h = ws + bigBase;
        U = h + hN;
        V = U + uvN;
    } else {
        // Old layout: big scratch lives inside the att output region; every
        // consumer runs before the separate kH overwrites it.
        h = att;
        U = att + hN;
        V = U + uvN;
    }

    kA_h_s       <<<512, 256, 0, stream>>>(doc, Ww, Wb, aw, h, s_src, s_dst, E1, E2);
    kBC_rank_top2<<<257, 256, 0, stream>>>(s_dst, red, perm);
    kD_gseg      <<<256, 256, 0, stream>>>(perm, E1, E2, s_dst, h, sortedS, E1s, E2s, seg1, seg2);
    kE_scan      <<<258, 256, 0, stream>>>(seg1, seg2, E1s, E2s, segUo, segVo, Psuf, Qpre);
    kF_uv        <<<256, 256, 0, stream>>>(perm, h, E1s, E2s, segUo, segVo, U, V);
    if (fused) {
        kGH_hout_att<<<512, 256, 0, stream>>>(s_src, s_dst, sortedS, Psuf, Qpre, red, ab,
                                              selfLink, U, V, h, E1, E2, hout, att);
    } else {
        kG_hout<<<4096, 256, 0, stream>>>(s_src, s_dst, sortedS, Psuf, Qpre, red, ab, selfLink,
                                          U, V, h, Aarr, Barr, rZ, Tarr, hout);
        kH_att <<<512,  256, 0, stream>>>(s_dst, E1, E2, Aarr, Barr, rZ, Tarr, selfLink, att);
    }
}